// Round 1
// 1910.970 us; speedup vs baseline: 11.1069x; 11.1069x over previous
//
#include <hip/hip_runtime.h>
#include <hip/hip_bf16.h>
#include <stdint.h>

typedef __hip_bfloat16 bf16;
typedef __attribute__((ext_vector_type(8))) short s16x8;   // 8 bf16 = 4 VGPR MFMA frag
typedef __attribute__((ext_vector_type(4))) float f32x4;   // MFMA 16x16 accumulator

// Problem constants: B=8, C=128, H=W=256, J=19, D=64, NH=128
// ws layout (float offsets)
#define OFF_NZT   0          // [8][256][256] transposed noise
#define OFF_MU    524288     // [8][19][64]
#define OFF_MEAN  534016     // [1024]
#define OFF_RSTD  535040     // [1024]
#define OFF_WC    536064     // [16][19][128] collapsed conv1 weights
#define OFF_T4G   574976     // [8][20][16][128] parity/cell-grouped gamma_avg table
#define OFF_T4B   902656     // [8][20][16][128]
#define OFF_WBF   1230336    // bf16 [2(hi/lo)][9][256][128]  (294912 floats)
#define OFF_NT    1525248    // [16 rs][5 nib][16 val][128] class-nibble sums of Wc
#define OFF_BITS  1689088    // [8][128][128] uint32 class bitmasks
// total = 1820160 floats = 7,280,640 bytes

#define WLO_OFF   294912     // ushort offset of lo-half weights inside OFF_WBF

// ---------------- K0: transpose noise (B,W,H,1) -> [b][h][w] ----------------
__global__ void k_nzT(const float* __restrict__ noise, float* __restrict__ nzT){
    int i = blockIdx.x*256 + threadIdx.x;          // 524288
    int b = i >> 16, r = i & 65535;
    int h = r >> 8, w = r & 255;
    nzT[i] = noise[(b<<16) + (w<<8) + h];
}

// ---------------- K1: mu[b][j][o] = relu(fc_b + fc_w @ style) ----------------
__global__ void k_mu(const float* __restrict__ style, const float* __restrict__ fcw,
                     const float* __restrict__ fcb, float* __restrict__ mu){
    int blk = blockIdx.x;            // 152 = 8*19
    int b = blk / 19, j = blk % 19;
    int o = threadIdx.x;             // 64
    const float* wr = fcw + (j*64 + o)*64;
    const float* sr = style + (b*19 + j)*64;
    float acc = fcb[j*64 + o];
    for (int i = 0; i < 64; i++) acc = fmaf(wr[i], sr[i], acc);
    mu[(b*19 + j)*64 + o] = fmaxf(acc, 0.f);
}

// ---------------- K2: instance-norm stats over (x + noise*nv) ----------------
__global__ void k_stats(const float* __restrict__ x, const float* __restrict__ nzT,
                        const float* __restrict__ nvar, float* __restrict__ meanv,
                        float* __restrict__ rstdv){
    int bc = blockIdx.x;             // 1024
    int b = bc >> 7, c = bc & 127;
    float nv = nvar[c];
    const float* xp  = x   + ((size_t)bc << 16);
    const float* np_ = nzT + ((size_t)b  << 16);
    float s1 = 0.f, s2 = 0.f;
    for (int k = 0; k < 256; k++){
        int idx = (k << 8) + threadIdx.x;
        float v = xp[idx] + nv * np_[idx];
        s1 += v; s2 = fmaf(v, v, s2);
    }
    for (int o = 32; o > 0; o >>= 1){ s1 += __shfl_down(s1, o, 64); s2 += __shfl_down(s2, o, 64); }
    __shared__ float r1[4], r2[4];
    int wid = threadIdx.x >> 6;
    if ((threadIdx.x & 63) == 0){ r1[wid] = s1; r2[wid] = s2; }
    __syncthreads();
    if (threadIdx.x == 0){
        float t1 = r1[0]+r1[1]+r1[2]+r1[3];
        float t2 = r2[0]+r2[1]+r2[2]+r2[3];
        float m = t1 * (1.f/65536.f);
        float var = t2 * (1.f/65536.f) - m*m;
        meanv[bc] = m;
        rstdv[bc] = rsqrtf(var + 1e-5f);
    }
}

// ---------------- K3: collapsed conv1 weights Wc[rs][j][n] ----------------
__global__ void k_wc(const float* __restrict__ w1, float* __restrict__ wc){
    int rs = blockIdx.x;             // 16
    int n  = threadIdx.x;            // 128
    int ry = (rs>>3)&1, rx = (rs>>2)&1, sy = (rs>>1)&1, sx = rs&1;
    for (int j = 0; j < 19; j++){
        float acc = 0.f;
        for (int dy = 0; dy < 3; dy++){
            bool iy = (ry==0) ? (sy==0 ? (dy==0) : (dy>=1)) : (sy==0 ? (dy<=1) : (dy==2));
            if (!iy) continue;
            for (int dx = 0; dx < 3; dx++){
                bool ix = (rx==0) ? (sx==0 ? (dx==0) : (dx>=1)) : (sx==0 ? (dx<=1) : (dx==2));
                if (ix) acc += w1[(n*19 + j)*9 + dy*3 + dx];
            }
        }
        wc[(rs*19 + j)*128 + n] = acc;
    }
}

// ---------------- K3b: nibble LUT over Wc classes ----------------
// NT[rs][ni][v][n] = sum over set bits k of v (class j = 4*ni+k, j<19) of Wc[rs][j][n]
__global__ void k_nib(const float* __restrict__ wc, float* __restrict__ nt){
    int v  = blockIdx.x;   // 16
    int ni = blockIdx.y;   // 5
    int rs = blockIdx.z;   // 16
    int n  = threadIdx.x;  // 128
    float acc = 0.f;
    #pragma unroll
    for (int k = 0; k < 4; k++){
        int j = 4*ni + k;
        if (((v >> k) & 1) && j < 19) acc += wc[(rs*19 + j)*128 + n];
    }
    nt[((rs*5 + ni)*16 + v)*128 + n] = acc;
}

// ---------------- K4: parity/cell-grouped avg-branch tables ----------------
// T4[b][j][par(ry,rx)][cell(cy,cx)][c] = sum over taps (dy in S(ry,cy), dx in S(rx,cx))
//   of sum_d mu[b][j][d]*cw[c][d][dy*3+dx].  Row j=19 = zeros ("uncovered").
__global__ void k_t4(const float* __restrict__ cgw, const float* __restrict__ cbw,
                     const float* __restrict__ mu, float* __restrict__ T4g,
                     float* __restrict__ T4b){
    int pc = blockIdx.x;             // 16: par*4 + cell
    int j  = blockIdx.y;             // 20
    int b  = blockIdx.z;             // 8
    int c  = threadIdx.x;            // 128
    int par = pc >> 2, cell = pc & 3;
    int ry = par>>1, rx = par&1, cy = cell>>1, cx = cell&1;
    // tap-row bitmasks: S(0,0)={0}, S(0,1)={1,2}, S(1,0)={0,1}, S(1,1)={2}
    int my_ = (ry==0) ? (cy==0 ? 1 : 6) : (cy==0 ? 3 : 4);
    int mx_ = (rx==0) ? (cx==0 ? 1 : 6) : (cx==0 ? 3 : 4);
    float ag = 0.f, ab = 0.f;
    if (j < 19){
        const float* mup = mu + (b*19 + j)*64;
        for (int dy = 0; dy < 3; dy++){
            if (!((my_>>dy)&1)) continue;
            for (int dx = 0; dx < 3; dx++){
                if (!((mx_>>dx)&1)) continue;
                int t = dy*3 + dx;
                const float* wg = cgw + (size_t)c*576 + t;
                const float* wb = cbw + (size_t)c*576 + t;
                for (int d = 0; d < 64; d++){
                    float mv = mup[d];
                    ag = fmaf(wg[d*9], mv, ag);
                    ab = fmaf(wb[d*9], mv, ab);
                }
            }
        }
    }
    int o = ((b*20 + j)*16 + pc)*128 + c;
    T4g[o] = ag; T4b[o] = ab;
}

// ---------------- K5: class bitmasks at half-res ----------------
__global__ void k_bits(const float* __restrict__ segmap, unsigned* __restrict__ bits){
    int i = blockIdx.x*256 + threadIdx.x;    // 131072
    int b = i >> 14, q = i & 16383;
    unsigned m = 0;
    for (int j = 0; j < 19; j++)
        if (segmap[((size_t)(b*19 + j) << 14) + q] > 0.f) m |= (1u << j);
    bits[i] = m;
}

// ---------------- K5b: spade conv2 weights -> bf16 hi/lo, [t][ct][n] ----------------
// ct = c for gamma (0..127), 128+c for beta.  w = hi + lo (both bf16) keeps fp32 accuracy.
__global__ void k_wbf(const float* __restrict__ sgw, const float* __restrict__ sbw,
                      bf16* __restrict__ dst){
    int t  = blockIdx.x;             // 9
    int ct = blockIdx.y;             // 256
    int n  = threadIdx.x;            // 128
    const float* src = (ct < 128) ? sgw : sbw;
    int c = ct & 127;
    float w = src[((size_t)(c*128 + n))*9 + t];
    bf16 h = __float2bfloat16(w);
    float hf = __bfloat162float(h);
    bf16 l = __float2bfloat16(w - hf);
    int idx = (t*256 + ct)*128 + n;
    dst[idx] = h;
    dst[WLO_OFF + idx] = l;
}

// ---------------- K6: fused final (MFMA spade conv + epilogue) ----------------
// Block: 256 threads = 4 waves, 16x8 pixel tile.
// Phase A: half-res class masks (halo)        -> segb[60]
// Phase B: actv halo tile bf16 (XOR-swizzled) -> actvS[180][128]
// Phase C: gamma_s/beta_s = MFMA GEMM: A=actv(LDS), B=Whi/Wlo(global), K=9*128
//          wave w owns channels [32w,32w+32) for both gamma and beta.
// Epilogue: 4-cell grouped avg-branch tables + instance-norm + blend + store.
__global__ __launch_bounds__(256, 2) void kf_final(
    const float* __restrict__ x, const float* __restrict__ nvar,
    const float* __restrict__ bgam, const float* __restrict__ bbet,
    const float* __restrict__ cgb, const float* __restrict__ cbb,
    const float* __restrict__ ssb, const float* __restrict__ sgb,
    const float* __restrict__ sbb,
    const float* __restrict__ ws, const unsigned* __restrict__ bitsws,
    float* __restrict__ out)
{
    const float* nzT   = ws + OFF_NZT;
    const float* meanv = ws + OFF_MEAN;
    const float* rstdv = ws + OFF_RSTD;
    const float* wsNT  = ws + OFF_NT;
    const float* T4gp  = ws + OFF_T4G;
    const float* T4bp  = ws + OFF_T4B;
    const bf16*  Wh    = (const bf16*)(ws + OFF_WBF);
    const bf16*  Wl    = Wh + WLO_OFF;

    const int gx = blockIdx.x;   // 16 tiles of 16 px wide
    const int gy = blockIdx.y;   // 32 tiles of 8 px tall
    const int b  = blockIdx.z;
    const int tid = threadIdx.x;

    __shared__ unsigned segb[60];                    // 6 x 10 half-res masks (halo)
    __shared__ __align__(16) bf16 actvS[180*128];    // swizzled: elem(sp,n) at sp*128 + (n ^ ((sp&7)<<3))

    // ---- Phase A ----
    if (tid < 60){
        int ly = tid / 10, lx = tid % 10;
        int qy = 4*gy - 1 + ly, qx = 8*gx - 1 + lx;
        unsigned m = 0;
        if (qy >= 0 && qy < 128 && qx >= 0 && qx < 128)
            m = bitsws[(b<<14) + (qy<<7) + qx];
        segb[tid] = m;
    }
    __syncthreads();

    // ---- Phase B: actv tile via nibble LUT (wave-uniform masks) ----
    {
        const int n = tid & 127;
        const int half = tid >> 7;            // wave-aligned: waves 0,1 -> half 0
        const float bias = ssb[n];
        int ay = 5*half, ax = 0;
        for (int s0 = 0; s0 < 90; s0++){
            int sp = 90*half + s0;
            int a_y = 8*gy - 1 + ay;
            int a_x = 16*gx - 1 + ax;
            float res = 0.f;
            if (a_y >= 0 && a_y < 256 && a_x >= 0 && a_x < 256){
                int ry = a_y & 1, rx = a_x & 1;
                int uy = a_y >> 1, ux = a_x >> 1;
                float acc = bias;
                #pragma unroll
                for (int sy = 0; sy < 2; sy++){
                    int ly = uy + sy - 1 + ry - (4*gy - 1);
                    #pragma unroll
                    for (int sx = 0; sx < 2; sx++){
                        int lx = ux + sx - 1 + rx - (8*gx - 1);
                        unsigned m = segb[ly*10 + lx];
                        m = __builtin_amdgcn_readfirstlane(m);   // wave-uniform -> scalar path
                        const float* nt = wsNT + (((ry*2+rx)*2+sy)*2+sx)*10240 + n;
                        #pragma unroll
                        for (int ni = 0; ni < 5; ni++)
                            acc += nt[(ni<<11) + (((m >> (4*ni)) & 15) << 7)];
                    }
                }
                res = fmaxf(acc, 0.f);
            }
            actvS[(sp<<7) + (n ^ ((sp&7)<<3))] = __float2bfloat16(res);
            if (++ax == 18){ ax = 0; ++ay; }
        }
    }
    __syncthreads();

    // ---- Phase C: MFMA GEMM ----
    const int lane = tid & 63;
    const int wv   = tid >> 6;               // 4 waves
    const int colA = lane & 15;              // A/B/D col index
    const int klo  = (lane >> 4) << 3;       // k-chunk base within K=32
    const int cL   = 32*wv + colA;           // low channel owned by this lane
    const int cH   = cL + 16;

    f32x4 acc[8][4];                         // [M-tile(pixel row)][g0,g1,b0,b1]
    {
        float g0 = sgb[cL], g1 = sgb[cH], b0 = sbb[cL], b1 = sbb[cH];
        #pragma unroll
        for (int m = 0; m < 8; m++){
            acc[m][0] = (f32x4){g0,g0,g0,g0};
            acc[m][1] = (f32x4){g1,g1,g1,g1};
            acc[m][2] = (f32x4){b0,b0,b0,b0};
            acc[m][3] = (f32x4){b1,b1,b1,b1};
        }
    }
    const int wbo0 = ((2*wv    )*16 + colA)*128 + klo;   // gamma tile lo
    const int wbo1 = ((2*wv + 1)*16 + colA)*128 + klo;   // gamma tile hi
    const int wbo2 = ((8 + 2*wv)*16 + colA)*128 + klo;   // beta tile lo
    const int wbo3 = ((9 + 2*wv)*16 + colA)*128 + klo;   // beta tile hi

    #pragma unroll 1
    for (int kst = 0; kst < 36; kst++){
        const int t  = kst >> 2;
        const int n0 = (kst & 3) << 5;
        const int dy = t / 3, dx = t - 3*dy;
        const int arb = dy*18 + colA + dx;               // LDS row for m=0
        const int wo  = t*32768 + n0;                    // (t*256)*128 + n0

        const s16x8 b0h = *(const s16x8*)(Wh + wbo0 + wo);
        const s16x8 b1h = *(const s16x8*)(Wh + wbo1 + wo);
        const s16x8 b2h = *(const s16x8*)(Wh + wbo2 + wo);
        const s16x8 b3h = *(const s16x8*)(Wh + wbo3 + wo);
        const s16x8 b0l = *(const s16x8*)(Wl + wbo0 + wo);
        const s16x8 b1l = *(const s16x8*)(Wl + wbo1 + wo);
        const s16x8 b2l = *(const s16x8*)(Wl + wbo2 + wo);
        const s16x8 b3l = *(const s16x8*)(Wl + wbo3 + wo);

        #pragma unroll
        for (int m = 0; m < 8; m++){
            const int ar = arb + m*18;
            const s16x8 am = *(const s16x8*)&actvS[ar*128 + ((n0 + klo) ^ ((ar & 7) << 3))];
            acc[m][0] = __builtin_amdgcn_mfma_f32_16x16x32_bf16(am, b0h, acc[m][0], 0, 0, 0);
            acc[m][0] = __builtin_amdgcn_mfma_f32_16x16x32_bf16(am, b0l, acc[m][0], 0, 0, 0);
            acc[m][1] = __builtin_amdgcn_mfma_f32_16x16x32_bf16(am, b1h, acc[m][1], 0, 0, 0);
            acc[m][1] = __builtin_amdgcn_mfma_f32_16x16x32_bf16(am, b1l, acc[m][1], 0, 0, 0);
            acc[m][2] = __builtin_amdgcn_mfma_f32_16x16x32_bf16(am, b2h, acc[m][2], 0, 0, 0);
            acc[m][2] = __builtin_amdgcn_mfma_f32_16x16x32_bf16(am, b2l, acc[m][2], 0, 0, 0);
            acc[m][3] = __builtin_amdgcn_mfma_f32_16x16x32_bf16(am, b3h, acc[m][3], 0, 0, 0);
            acc[m][3] = __builtin_amdgcn_mfma_f32_16x16x32_bf16(am, b3l, acc[m][3], 0, 0, 0);
        }
    }

    // ---- Epilogue ----
    const float ga = 1.f/(1.f + __expf(-bgam[0]));
    const float ba = 1.f/(1.f + __expf(-bbet[0]));
    const float cgbL = cgb[cL], cgbH = cgb[cH];
    const float cbbL = cbb[cL], cbbH = cbb[cH];
    const float mL = meanv[(b<<7)+cL], rL = rstdv[(b<<7)+cL];
    const float mH = meanv[(b<<7)+cH], rH = rstdv[(b<<7)+cH];
    const float nvL = nvar[cL], nvH = nvar[cH];
    const int pxg = (lane >> 4) << 2;         // D-row group base (pixel col)

    #pragma unroll
    for (int m = 0; m < 8; m++){
        const int py  = 8*gy + m;
        const int qy0 = ((m-1) >> 1) + 1;     // local half-res cell row (arith shift)
        #pragma unroll
        for (int r = 0; r < 4; r++){
            const int tpx = pxg + r;
            const int px  = 16*gx + tpx;
            const int qx0 = ((tpx-1) >> 1) + 1;
            const int par4 = (((m & 1) << 1) | (tpx & 1)) << 2;
            float g0 = cgbL, g1 = cgbH, bv0 = cbbL, bv1 = cbbH;
            #pragma unroll
            for (int cell = 0; cell < 4; cell++){
                unsigned msk = segb[(qy0 + (cell>>1))*10 + qx0 + (cell&1)];
                int lbl = msk ? (31 - __builtin_clz(msk)) : 19;
                int off = ((b*20 + lbl)*16 + par4 + cell)*128;
                g0  += T4gp[off + cL];  g1  += T4gp[off + cH];
                bv0 += T4bp[off + cL];  bv1 += T4bp[off + cH];
            }
            const float nz = nzT[(b<<16) + (py<<8) + px];
            const int pbase = (py<<8) + px;
            {   // low channel
                const float gf  = ga*g0  + (1.f - ga)*acc[m][0][r];
                const float bfv = ba*bv0 + (1.f - ba)*acc[m][2][r];
                const int xi = b*8388608 + (cL<<16) + pbase;
                const float v = x[xi] + nvL*nz;
                const float nrm = (v - mL)*rL;
                out[xi] = nrm*(1.f + gf) + bfv;
            }
            {   // high channel
                const float gf  = ga*g1  + (1.f - ga)*acc[m][1][r];
                const float bfv = ba*bv1 + (1.f - ba)*acc[m][3][r];
                const int xi = b*8388608 + (cH<<16) + pbase;
                const float v = x[xi] + nvH*nz;
                const float nrm = (v - mH)*rH;
                out[xi] = nrm*(1.f + gf) + bfv;
            }
        }
    }
}

extern "C" void kernel_launch(void* const* d_in, const int* in_sizes, int n_in,
                              void* d_out, int out_size, void* d_ws, size_t ws_size,
                              hipStream_t stream) {
    const float* x     = (const float*)d_in[0];
    const float* seg   = (const float*)d_in[1];
    const float* style = (const float*)d_in[2];
    const float* noise = (const float*)d_in[3];
    const float* nvar  = (const float*)d_in[4];
    const float* bgam  = (const float*)d_in[5];
    const float* bbet  = (const float*)d_in[6];
    const float* fcw   = (const float*)d_in[7];
    const float* fcb   = (const float*)d_in[8];
    const float* cgw   = (const float*)d_in[9];
    const float* cgb   = (const float*)d_in[10];
    const float* cbw   = (const float*)d_in[11];
    const float* cbb   = (const float*)d_in[12];
    const float* ssw   = (const float*)d_in[13];
    const float* ssb   = (const float*)d_in[14];
    const float* sgw   = (const float*)d_in[15];
    const float* sgb   = (const float*)d_in[16];
    const float* sbw   = (const float*)d_in[17];
    const float* sbb   = (const float*)d_in[18];
    float* out = (float*)d_out;

    float* ws = (float*)d_ws;
    unsigned* bits = (unsigned*)(ws + OFF_BITS);

    k_nzT  <<<2048, 256, 0, stream>>>(noise, ws + OFF_NZT);
    k_mu   <<<152,  64,  0, stream>>>(style, fcw, fcb, ws + OFF_MU);
    k_stats<<<1024, 256, 0, stream>>>(x, ws + OFF_NZT, nvar, ws + OFF_MEAN, ws + OFF_RSTD);
    k_wc   <<<16,   128, 0, stream>>>(ssw, ws + OFF_WC);
    k_nib  <<<dim3(16,5,16), 128, 0, stream>>>(ws + OFF_WC, ws + OFF_NT);
    k_t4   <<<dim3(16,20,8), 128, 0, stream>>>(cgw, cbw, ws + OFF_MU, ws + OFF_T4G, ws + OFF_T4B);
    k_bits <<<512,  256, 0, stream>>>(seg, bits);
    k_wbf  <<<dim3(9,256), 128, 0, stream>>>(sgw, sbw, (bf16*)(ws + OFF_WBF));
    kf_final<<<dim3(16,32,8), 256, 0, stream>>>(x, nvar, bgam, bbet, cgb, cbb,
                                                ssb, sgb, sbb, ws, bits, out);
}

// Round 2
// 1276.716 us; speedup vs baseline: 16.6246x; 1.4968x over previous
//
#include <hip/hip_runtime.h>
#include <hip/hip_bf16.h>
#include <stdint.h>

typedef __hip_bfloat16 bf16;
typedef __attribute__((ext_vector_type(8))) short s16x8;   // 8 bf16 = 4 VGPR MFMA frag
typedef __attribute__((ext_vector_type(4))) float f32x4;   // MFMA 16x16 accumulator

// Problem constants: B=8, C=128, H=W=256, J=19, D=64, NH=128
// ws layout (float offsets)
#define OFF_NZT   0          // [8][256][256] transposed noise
#define OFF_MU    524288     // [8][19][64]
#define OFF_MEAN  534016     // [1024]
#define OFF_RSTD  535040     // [1024]
#define OFF_WC    536064     // [16][19][128] collapsed conv1 weights (fp32)
#define OFF_T4G   574976     // [8][20][16][128] parity/cell-grouped gamma_avg table
#define OFF_T4B   902656     // [8][20][16][128]
#define OFF_WBF   1230336    // bf16 [2 hl][9][256][128] spade conv2 weights (294912 floats)
#define OFF_CWT   1525248    // [2 gb][9 t][64 d][128 c] transposed conv_gamma/beta weights
#define OFF_WCB   1672704    // bf16 [4 par][2 hl][128 c][96 k] conv1 weights for MFMA (49152 floats)
#define OFF_BITS  1721856    // [8][128][128] uint32 class bitmasks
// total = 1852928 floats = 7.4 MB

#define WLO_OFF   294912     // bf16-offset of lo-half inside OFF_WBF

// ---------------- K0: transpose noise (B,W,H,1) -> [b][h][w], LDS-tiled ----------------
__global__ void k_nzT(const float* __restrict__ noise, float* __restrict__ nzT){
    __shared__ float lds[64][65];
    const int b  = blockIdx.z;
    const int hb = blockIdx.x * 64;
    const int wb = blockIdx.y * 64;
    const int tx = threadIdx.x & 63;     // inner (coalesced) index
    const int ty = threadIdx.x >> 6;     // 0..3
    #pragma unroll
    for (int i = 0; i < 16; i++){
        int wl = ty + 4*i;
        lds[wl][tx] = noise[(b<<16) + (wb + wl)*256 + hb + tx];
    }
    __syncthreads();
    #pragma unroll
    for (int i = 0; i < 16; i++){
        int hl = ty + 4*i;
        nzT[(b<<16) + (hb + hl)*256 + wb + tx] = lds[tx][hl];
    }
}

// ---------------- K1: mu[b][j][o] = relu(fc_b + fc_w @ style) ----------------
__global__ void k_mu(const float* __restrict__ style, const float* __restrict__ fcw,
                     const float* __restrict__ fcb, float* __restrict__ mu){
    int blk = blockIdx.x;            // 152 = 8*19
    int b = blk / 19, j = blk % 19;
    int o = threadIdx.x;             // 64
    const float* wr = fcw + (j*64 + o)*64;
    const float* sr = style + (b*19 + j)*64;
    float acc = fcb[j*64 + o];
    for (int i = 0; i < 64; i++) acc = fmaf(wr[i], sr[i], acc);
    mu[(b*19 + j)*64 + o] = fmaxf(acc, 0.f);
}

// ---------------- K2: instance-norm stats over (x + noise*nv), float4 ----------------
__global__ void k_stats(const float* __restrict__ x, const float* __restrict__ nzT,
                        const float* __restrict__ nvar, float* __restrict__ meanv,
                        float* __restrict__ rstdv){
    int bc = blockIdx.x;             // 1024
    int b = bc >> 7, c = bc & 127;
    float nv = nvar[c];
    const float4* xp4 = (const float4*)(x   + ((size_t)bc << 16));
    const float4* np4 = (const float4*)(nzT + ((size_t)b  << 16));
    float s1 = 0.f, s2 = 0.f;
    for (int k = 0; k < 64; k++){
        int idx = (k << 8) + threadIdx.x;
        float4 xv = xp4[idx], nz = np4[idx];
        float v0 = xv.x + nv*nz.x, v1 = xv.y + nv*nz.y;
        float v2 = xv.z + nv*nz.z, v3 = xv.w + nv*nz.w;
        s1 += v0 + v1 + v2 + v3;
        s2 = fmaf(v0, v0, s2); s2 = fmaf(v1, v1, s2);
        s2 = fmaf(v2, v2, s2); s2 = fmaf(v3, v3, s2);
    }
    for (int o = 32; o > 0; o >>= 1){ s1 += __shfl_down(s1, o, 64); s2 += __shfl_down(s2, o, 64); }
    __shared__ float r1[4], r2[4];
    int wid = threadIdx.x >> 6;
    if ((threadIdx.x & 63) == 0){ r1[wid] = s1; r2[wid] = s2; }
    __syncthreads();
    if (threadIdx.x == 0){
        float t1 = r1[0]+r1[1]+r1[2]+r1[3];
        float t2 = r2[0]+r2[1]+r2[2]+r2[3];
        float m = t1 * (1.f/65536.f);
        float var = t2 * (1.f/65536.f) - m*m;
        meanv[bc] = m;
        rstdv[bc] = rsqrtf(var + 1e-5f);
    }
}

// ---------------- K3: collapsed conv1 weights Wc[rs][j][n] ----------------
__global__ void k_wc(const float* __restrict__ w1, float* __restrict__ wc){
    int rs = blockIdx.x;             // 16
    int n  = threadIdx.x;            // 128
    int ry = (rs>>3)&1, rx = (rs>>2)&1, sy = (rs>>1)&1, sx = rs&1;
    for (int j = 0; j < 19; j++){
        float acc = 0.f;
        for (int dy = 0; dy < 3; dy++){
            bool iy = (ry==0) ? (sy==0 ? (dy==0) : (dy>=1)) : (sy==0 ? (dy<=1) : (dy==2));
            if (!iy) continue;
            for (int dx = 0; dx < 3; dx++){
                bool ix = (rx==0) ? (sx==0 ? (dx==0) : (dx>=1)) : (sx==0 ? (dx<=1) : (dx==2));
                if (ix) acc += w1[(n*19 + j)*9 + dy*3 + dx];
            }
        }
        wc[(rs*19 + j)*128 + n] = acc;
    }
}

// ---------------- K3b: Wc -> bf16 hi/lo MFMA B-matrix  WBT[par][hl][c][k=96] ----------------
// k = so*24 + j (j<19 real, rest zero); rs = par*4 + so.
__global__ void k_wcb(const float* __restrict__ wc, bf16* __restrict__ wbt){
    int k   = blockIdx.x;   // 96
    int par = blockIdx.y;   // 4
    int c   = threadIdx.x;  // 128
    int so = k / 24, j = k - so*24;
    float w = (j < 19) ? wc[((par*4 + so)*19 + j)*128 + c] : 0.f;
    bf16 h = __float2bfloat16(w);
    float hf = __bfloat162float(h);
    bf16 l = __float2bfloat16(w - hf);
    wbt[((size_t)((par*2 + 0)*128 + c))*96 + k] = h;
    wbt[((size_t)((par*2 + 1)*128 + c))*96 + k] = l;
}

// ---------------- K3c: transpose conv_gamma/beta weights -> [gb][t][d][c] ----------------
__global__ void k_cwT(const float* __restrict__ cgw, const float* __restrict__ cbw,
                      float* __restrict__ cwt){
    int d  = blockIdx.x;    // 64
    int t  = blockIdx.y;    // 9
    int gb = blockIdx.z;    // 2
    int c  = threadIdx.x;   // 128
    const float* src = gb ? cbw : cgw;
    cwt[((size_t)((gb*9 + t)*64 + d))*128 + c] = src[(size_t)c*576 + d*9 + t];
}

// ---------------- K4: parity/cell-grouped avg-branch tables (coalesced) ----------------
__global__ void k_t4(const float* __restrict__ cwt, const float* __restrict__ mu,
                     float* __restrict__ T4g, float* __restrict__ T4b){
    int pc = blockIdx.x;             // 16: par*4 + cell
    int j  = blockIdx.y;             // 20
    int b  = blockIdx.z;             // 8
    int c  = threadIdx.x;            // 128
    int par = pc >> 2, cell = pc & 3;
    int ry = par>>1, rx = par&1, cy = cell>>1, cx = cell&1;
    int my_ = (ry==0) ? (cy==0 ? 1 : 6) : (cy==0 ? 3 : 4);
    int mx_ = (rx==0) ? (cx==0 ? 1 : 6) : (cx==0 ? 3 : 4);
    float ag = 0.f, ab = 0.f;
    if (j < 19){
        const float* mup = mu + (b*19 + j)*64;
        for (int dy = 0; dy < 3; dy++){
            if (!((my_>>dy)&1)) continue;
            for (int dx = 0; dx < 3; dx++){
                if (!((mx_>>dx)&1)) continue;
                int t = dy*3 + dx;
                const float* wg = cwt + (size_t)(t*64)*128 + c;
                const float* wb = cwt + (size_t)((9 + t)*64)*128 + c;
                for (int d = 0; d < 64; d++){
                    float mv = mup[d];
                    ag = fmaf(wg[d<<7], mv, ag);
                    ab = fmaf(wb[d<<7], mv, ab);
                }
            }
        }
    }
    int o = ((b*20 + j)*16 + pc)*128 + c;
    T4g[o] = ag; T4b[o] = ab;
}

// ---------------- K5: class bitmasks at half-res ----------------
__global__ void k_bits(const float* __restrict__ segmap, unsigned* __restrict__ bits){
    int i = blockIdx.x*256 + threadIdx.x;    // 131072
    int b = i >> 14, q = i & 16383;
    unsigned m = 0;
    for (int j = 0; j < 19; j++)
        if (segmap[((size_t)(b*19 + j) << 14) + q] > 0.f) m |= (1u << j);
    bits[i] = m;
}

// ---------------- K5b: spade conv2 weights -> bf16 hi/lo, [t][ct][n] ----------------
__global__ void k_wbf(const float* __restrict__ sgw, const float* __restrict__ sbw,
                      bf16* __restrict__ dst){
    int t  = blockIdx.x;             // 9
    int ct = blockIdx.y;             // 256
    int n  = threadIdx.x;            // 128
    const float* src = (ct < 128) ? sgw : sbw;
    int c = ct & 127;
    float w = src[((size_t)(c*128 + n))*9 + t];
    bf16 h = __float2bfloat16(w);
    float hf = __bfloat162float(h);
    bf16 l = __float2bfloat16(w - hf);
    int idx = (t*256 + ct)*128 + n;
    dst[idx] = h;
    dst[WLO_OFF + idx] = l;
}

// ---------------- K6: fused final (all-MFMA) ----------------
// Block: 256 threads = 4 waves, 16x8 pixel tile.
// Phase A : half-res class masks (halo)              -> segb[60]
// Phase B': actv tile via 4 per-parity MFMA GEMMs:
//           A = binary masks from segb bits (exact bf16), B = WBT hi/lo, relu -> actvS
// Phase C : gamma_s/beta_s MFMA GEMM (K = 9*128), A = actvS, B = Wh/Wl
// Epilogue: 4-cell avg tables + instance-norm + blend + store.
__global__ __launch_bounds__(256, 2) void kf_final(
    const float* __restrict__ x, const float* __restrict__ nvar,
    const float* __restrict__ bgam, const float* __restrict__ bbet,
    const float* __restrict__ cgb, const float* __restrict__ cbb,
    const float* __restrict__ ssb, const float* __restrict__ sgb,
    const float* __restrict__ sbb,
    const float* __restrict__ ws, const unsigned* __restrict__ bitsws,
    float* __restrict__ out)
{
    const float* nzT   = ws + OFF_NZT;
    const float* meanv = ws + OFF_MEAN;
    const float* rstdv = ws + OFF_RSTD;
    const float* T4gp  = ws + OFF_T4G;
    const float* T4bp  = ws + OFF_T4B;
    const bf16*  Wh    = (const bf16*)(ws + OFF_WBF);
    const bf16*  Wl    = Wh + WLO_OFF;
    const bf16*  WBT   = (const bf16*)(ws + OFF_WCB);

    const int gx = blockIdx.x;   // 16 tiles of 16 px wide
    const int gy = blockIdx.y;   // 32 tiles of 8 px tall
    const int b  = blockIdx.z;
    const int tid = threadIdx.x;

    __shared__ unsigned segb[60];                    // 6 x 10 half-res masks (halo)
    __shared__ __align__(16) bf16 actvS[180*128];    // elem(sp,n) at sp*128 + (n ^ ((sp&7)<<3))

    // ---- Phase A ----
    if (tid < 60){
        int ly = tid / 10, lx = tid % 10;
        int qy = 4*gy - 1 + ly, qx = 8*gx - 1 + lx;
        unsigned m = 0;
        if (qy >= 0 && qy < 128 && qx >= 0 && qx < 128)
            m = bitsws[(b<<14) + (qy<<7) + qx];
        segb[tid] = m;
    }
    __syncthreads();

    const int lane = tid & 63;
    const int wv   = tid >> 6;               // 4 waves
    const int colA = lane & 15;
    const int klo8 = (lane >> 4) << 3;       // k-chunk base within 32

    // ---- Phase B': actv via per-parity MFMA ----
    {
        const float bias0 = ssb[32*wv + colA];
        const float bias1 = ssb[32*wv + 16 + colA];
        #pragma unroll 1
        for (int par = 0; par < 4; par++){
            const int ry = par >> 1, rx = par & 1;
            // B-frags: [kst][nt][hl]
            s16x8 bw[3][2][2];
            #pragma unroll
            for (int kst = 0; kst < 3; kst++)
                #pragma unroll
                for (int nt = 0; nt < 2; nt++)
                    #pragma unroll
                    for (int hl = 0; hl < 2; hl++){
                        int c = 32*wv + 16*nt + colA;
                        bw[kst][nt][hl] = *(const s16x8*)(WBT +
                            ((size_t)((par*2 + hl)*128 + c))*96 + 32*kst + klo8);
                    }
            f32x4 a2[3][2];
            #pragma unroll
            for (int mt = 0; mt < 3; mt++){
                a2[mt][0] = (f32x4){bias0,bias0,bias0,bias0};
                a2[mt][1] = (f32x4){bias1,bias1,bias1,bias1};
            }
            #pragma unroll
            for (int mt = 0; mt < 3; mt++){
                const int p = mt*16 + colA;          // pixel index in parity group (0..47)
                unsigned m00=0, m01=0, m10=0, m11=0;
                if (p < 45){
                    int gy_i = (p*57) >> 9;          // p/9
                    int gx_i = p - gy_i*9;
                    int base = gy_i*10 + gx_i;       // ly = gy_i+sy, lx = gx_i+sx
                    m00 = segb[base];      m01 = segb[base + 1];
                    m10 = segb[base + 10]; m11 = segb[base + 11];
                }
                #pragma unroll
                for (int kst = 0; kst < 3; kst++){
                    const int kb = 32*kst + klo8;
                    const int so = (kb*43) >> 10;    // kb/24
                    const int jb = kb - so*24;
                    unsigned m = (so < 2) ? (so == 0 ? m00 : m01) : (so == 2 ? m10 : m11);
                    unsigned ms = m >> jb;
                    s16x8 af;
                    #pragma unroll
                    for (int i = 0; i < 8; i++)
                        af[i] = (short)(((ms >> i) & 1) ? 0x3F80 : 0);
                    a2[mt][0] = __builtin_amdgcn_mfma_f32_16x16x32_bf16(af, bw[kst][0][0], a2[mt][0], 0, 0, 0);
                    a2[mt][0] = __builtin_amdgcn_mfma_f32_16x16x32_bf16(af, bw[kst][0][1], a2[mt][0], 0, 0, 0);
                    a2[mt][1] = __builtin_amdgcn_mfma_f32_16x16x32_bf16(af, bw[kst][1][0], a2[mt][1], 0, 0, 0);
                    a2[mt][1] = __builtin_amdgcn_mfma_f32_16x16x32_bf16(af, bw[kst][1][1], a2[mt][1], 0, 0, 0);
                }
            }
            // store D -> actvS (relu, zero outside image)
            #pragma unroll
            for (int mt = 0; mt < 3; mt++){
                #pragma unroll
                for (int nt = 0; nt < 2; nt++){
                    const int c = 32*wv + 16*nt + colA;
                    #pragma unroll
                    for (int reg = 0; reg < 4; reg++){
                        int p = mt*16 + ((lane>>4)<<2) + reg;
                        if (p < 45){
                            int gy_i = (p*57) >> 9;
                            int gx_i = p - gy_i*9;
                            int ay = 2*gy_i + 1 - ry;
                            int ax = 2*gx_i + 1 - rx;
                            int a_y = 8*gy - 1 + ay, a_x = 16*gx - 1 + ax;
                            float v = fmaxf(a2[mt][nt][reg], 0.f);
                            if ((unsigned)a_y >= 256u || (unsigned)a_x >= 256u) v = 0.f;
                            int sp = ay*18 + ax;
                            actvS[(sp<<7) + (c ^ ((sp&7)<<3))] = __float2bfloat16(v);
                        }
                    }
                }
            }
        }
    }
    __syncthreads();

    // ---- Phase C: MFMA GEMM (gamma_s / beta_s) ----
    const int cL = 32*wv + colA;
    const int cH = cL + 16;

    f32x4 acc[8][4];                         // [pixel-row][g0,g1,b0,b1]
    {
        float g0 = sgb[cL], g1 = sgb[cH], b0 = sbb[cL], b1 = sbb[cH];
        #pragma unroll
        for (int m = 0; m < 8; m++){
            acc[m][0] = (f32x4){g0,g0,g0,g0};
            acc[m][1] = (f32x4){g1,g1,g1,g1};
            acc[m][2] = (f32x4){b0,b0,b0,b0};
            acc[m][3] = (f32x4){b1,b1,b1,b1};
        }
    }
    const int wbo0 = ((2*wv    )*16 + colA)*128 + klo8;   // gamma tile lo
    const int wbo1 = ((2*wv + 1)*16 + colA)*128 + klo8;   // gamma tile hi
    const int wbo2 = ((8 + 2*wv)*16 + colA)*128 + klo8;   // beta tile lo
    const int wbo3 = ((9 + 2*wv)*16 + colA)*128 + klo8;   // beta tile hi

    #pragma unroll 1
    for (int kst = 0; kst < 36; kst++){
        const int t  = kst >> 2;
        const int n0 = (kst & 3) << 5;
        const int dy = t / 3, dx = t - 3*dy;
        const int arb = dy*18 + colA + dx;               // LDS row for m=0
        const int wo  = t*32768 + n0;                    // (t*256)*128 + n0

        const s16x8 b0h = *(const s16x8*)(Wh + wbo0 + wo);
        const s16x8 b1h = *(const s16x8*)(Wh + wbo1 + wo);
        const s16x8 b2h = *(const s16x8*)(Wh + wbo2 + wo);
        const s16x8 b3h = *(const s16x8*)(Wh + wbo3 + wo);
        const s16x8 b0l = *(const s16x8*)(Wl + wbo0 + wo);
        const s16x8 b1l = *(const s16x8*)(Wl + wbo1 + wo);
        const s16x8 b2l = *(const s16x8*)(Wl + wbo2 + wo);
        const s16x8 b3l = *(const s16x8*)(Wl + wbo3 + wo);

        #pragma unroll
        for (int m = 0; m < 8; m++){
            const int ar = arb + m*18;
            const s16x8 am = *(const s16x8*)&actvS[ar*128 + ((n0 + klo8) ^ ((ar & 7) << 3))];
            acc[m][0] = __builtin_amdgcn_mfma_f32_16x16x32_bf16(am, b0h, acc[m][0], 0, 0, 0);
            acc[m][0] = __builtin_amdgcn_mfma_f32_16x16x32_bf16(am, b0l, acc[m][0], 0, 0, 0);
            acc[m][1] = __builtin_amdgcn_mfma_f32_16x16x32_bf16(am, b1h, acc[m][1], 0, 0, 0);
            acc[m][1] = __builtin_amdgcn_mfma_f32_16x16x32_bf16(am, b1l, acc[m][1], 0, 0, 0);
            acc[m][2] = __builtin_amdgcn_mfma_f32_16x16x32_bf16(am, b2h, acc[m][2], 0, 0, 0);
            acc[m][2] = __builtin_amdgcn_mfma_f32_16x16x32_bf16(am, b2l, acc[m][2], 0, 0, 0);
            acc[m][3] = __builtin_amdgcn_mfma_f32_16x16x32_bf16(am, b3h, acc[m][3], 0, 0, 0);
            acc[m][3] = __builtin_amdgcn_mfma_f32_16x16x32_bf16(am, b3l, acc[m][3], 0, 0, 0);
        }
    }

    // ---- Epilogue ----
    const float ga = 1.f/(1.f + __expf(-bgam[0]));
    const float ba = 1.f/(1.f + __expf(-bbet[0]));
    const float cgbL = cgb[cL], cgbH = cgb[cH];
    const float cbbL = cbb[cL], cbbH = cbb[cH];
    const float mL = meanv[(b<<7)+cL], rL = rstdv[(b<<7)+cL];
    const float mH = meanv[(b<<7)+cH], rH = rstdv[(b<<7)+cH];
    const float nvL = nvar[cL], nvH = nvar[cH];
    const int pxg = (lane >> 4) << 2;         // D-row group base (pixel col)

    #pragma unroll
    for (int m = 0; m < 8; m++){
        const int py  = 8*gy + m;
        const int qy0 = ((m-1) >> 1) + 1;     // local half-res cell row
        #pragma unroll
        for (int r = 0; r < 4; r++){
            const int tpx = pxg + r;
            const int px  = 16*gx + tpx;
            const int qx0 = ((tpx-1) >> 1) + 1;
            const int par4 = (((m & 1) << 1) | (tpx & 1)) << 2;
            float g0 = cgbL, g1 = cgbH, bv0 = cbbL, bv1 = cbbH;
            #pragma unroll
            for (int cell = 0; cell < 4; cell++){
                unsigned msk = segb[(qy0 + (cell>>1))*10 + qx0 + (cell&1)];
                int lbl = msk ? (31 - __builtin_clz(msk)) : 19;
                int off = ((b*20 + lbl)*16 + par4 + cell)*128;
                g0  += T4gp[off + cL];  g1  += T4gp[off + cH];
                bv0 += T4bp[off + cL];  bv1 += T4bp[off + cH];
            }
            const float nz = nzT[(b<<16) + (py<<8) + px];
            const int pbase = (py<<8) + px;
            {   // low channel
                const float gf  = ga*g0  + (1.f - ga)*acc[m][0][r];
                const float bfv = ba*bv0 + (1.f - ba)*acc[m][2][r];
                const int xi = b*8388608 + (cL<<16) + pbase;
                const float v = x[xi] + nvL*nz;
                const float nrm = (v - mL)*rL;
                out[xi] = nrm*(1.f + gf) + bfv;
            }
            {   // high channel
                const float gf  = ga*g1  + (1.f - ga)*acc[m][1][r];
                const float bfv = ba*bv1 + (1.f - ba)*acc[m][3][r];
                const int xi = b*8388608 + (cH<<16) + pbase;
                const float v = x[xi] + nvH*nz;
                const float nrm = (v - mH)*rH;
                out[xi] = nrm*(1.f + gf) + bfv;
            }
        }
    }
}

extern "C" void kernel_launch(void* const* d_in, const int* in_sizes, int n_in,
                              void* d_out, int out_size, void* d_ws, size_t ws_size,
                              hipStream_t stream) {
    const float* x     = (const float*)d_in[0];
    const float* seg   = (const float*)d_in[1];
    const float* style = (const float*)d_in[2];
    const float* noise = (const float*)d_in[3];
    const float* nvar  = (const float*)d_in[4];
    const float* bgam  = (const float*)d_in[5];
    const float* bbet  = (const float*)d_in[6];
    const float* fcw   = (const float*)d_in[7];
    const float* fcb   = (const float*)d_in[8];
    const float* cgw   = (const float*)d_in[9];
    const float* cgb   = (const float*)d_in[10];
    const float* cbw   = (const float*)d_in[11];
    const float* cbb   = (const float*)d_in[12];
    const float* ssw   = (const float*)d_in[13];
    const float* ssb   = (const float*)d_in[14];
    const float* sgw   = (const float*)d_in[15];
    const float* sgb   = (const float*)d_in[16];
    const float* sbw   = (const float*)d_in[17];
    const float* sbb   = (const float*)d_in[18];
    float* out = (float*)d_out;

    float* ws = (float*)d_ws;
    unsigned* bits = (unsigned*)(ws + OFF_BITS);

    k_nzT  <<<dim3(4,4,8),  256, 0, stream>>>(noise, ws + OFF_NZT);
    k_mu   <<<152,  64,  0, stream>>>(style, fcw, fcb, ws + OFF_MU);
    k_stats<<<1024, 256, 0, stream>>>(x, ws + OFF_NZT, nvar, ws + OFF_MEAN, ws + OFF_RSTD);
    k_wc   <<<16,   128, 0, stream>>>(ssw, ws + OFF_WC);
    k_wcb  <<<dim3(96,4),   128, 0, stream>>>(ws + OFF_WC, (bf16*)(ws + OFF_WCB));
    k_cwT  <<<dim3(64,9,2), 128, 0, stream>>>(cgw, cbw, ws + OFF_CWT);
    k_t4   <<<dim3(16,20,8),128, 0, stream>>>(ws + OFF_CWT, ws + OFF_MU, ws + OFF_T4G, ws + OFF_T4B);
    k_bits <<<512,  256, 0, stream>>>(seg, bits);
    k_wbf  <<<dim3(9,256),  128, 0, stream>>>(sgw, sbw, (bf16*)(ws + OFF_WBF));
    kf_final<<<dim3(16,32,8), 256, 0, stream>>>(x, nvar, bgam, bbet, cgb, cbb,
                                                ssb, sgb, sbb, ws, bits, out);
}